// Round 4
// baseline (259.441 us; speedup 1.0000x reference)
//
#include <hip/hip_runtime.h>

#define CIN    128
#define HH     56
#define WW_    56
#define NBATCH 32
#define COUT   256
#define KTOT   1152          // 9 taps * 128 ci  (k-order: kh, kw, ci)
#define PLANE  3136          // 56*56
#define HP     58            // padded H/W
#define BM     128           // c_out tile
#define BN     128           // pixel tile
#define BK     64            // k per step

#define WB_OFF   0                         // bf16 weights [256][9][128] in ws
#define XP_OFF   (1u << 20)                // padded bf16 input [32][58][58][128]
#define LSTR     66                        // prep LDS stride (shorts): 2-way bank alias = free

typedef __attribute__((ext_vector_type(8))) short bf16x8;
typedef __attribute__((ext_vector_type(4))) float f32x4;

__device__ __forceinline__ unsigned short f2bf(float f) {
    unsigned int u = __builtin_bit_cast(unsigned int, f);
    u += 0x7fffu + ((u >> 16) & 1u);   // RNE
    return (unsigned short)(u >> 16);
}

__device__ __forceinline__ void gl_lds16(const void* g, void* l) {
    __builtin_amdgcn_global_load_lds(
        (const __attribute__((address_space(1))) void*)g,
        (__attribute__((address_space(3))) void*)l, 16, 0, 0);
}

// ---- fused prep: blocks [0,1856) = input NCHW->padded NHWC bf16; [1856,1888) = weights ----
__global__ __launch_bounds__(256)
void prep(const float* __restrict__ in, const float* __restrict__ wt,
          unsigned short* __restrict__ xp, unsigned short* __restrict__ wb) {
    const int b = blockIdx.x;
    const int t = threadIdx.x;

    if (b >= NBATCH * HP) {               // weight conversion: 8 c_out rows per block
        const int o0 = (b - NBATCH * HP) * 8;
        for (int oo = 0; oo < 8; ++oo) {
            const float* src = wt + (size_t)(o0 + oo) * KTOT;
            unsigned short* dst = wb + (size_t)(o0 + oo) * KTOT;
            #pragma unroll
            for (int e = 0; e < 5; ++e) {
                const int idx = t + e * 256;       // = ci*9 + tap
                if (idx < KTOT) {
                    const int ci  = idx / 9;
                    const int tap = idx - ci * 9;
                    dst[tap * 128 + ci] = f2bf(src[idx]);
                }
            }
        }
        return;
    }

    const int n  = b / HP;
    const int ho = b - n * HP;
    uint4* orow = (uint4*)(xp + (((size_t)n * HP + ho) * HP) * CIN);  // 928 uint4/row

    if (ho == 0 || ho == HP - 1) {        // border rows: pure zeros
        #pragma unroll
        for (int e = 0; e < 4; ++e) {
            const int idx = t + e * 256;
            if (idx < 928) orow[idx] = (uint4){0u, 0u, 0u, 0u};
        }
        return;
    }

    __shared__ unsigned short L[CIN * LSTR];
    const int h  = ho - 1;
    const int f4 = t & 15;                // float4 slot within row (0..13 valid)
    const int cg = t >> 4;                // ci group 0..15
    if (f4 < 14) {
        const float* rowb = in + ((size_t)n * CIN) * PLANE + (size_t)h * WW_;
        #pragma unroll
        for (int g = 0; g < 8; ++g) {
            const int ci = cg + g * 16;
            const float4 v = *(const float4*)(rowb + (size_t)ci * PLANE + f4 * 4);
            unsigned lo = (unsigned)f2bf(v.x) | ((unsigned)f2bf(v.y) << 16);
            unsigned hi = (unsigned)f2bf(v.z) | ((unsigned)f2bf(v.w) << 16);
            *(unsigned*)&L[ci * LSTR + f4 * 4]     = lo;
            *(unsigned*)&L[ci * LSTR + f4 * 4 + 2] = hi;
        }
    }
    __syncthreads();

    #pragma unroll
    for (int e = 0; e < 4; ++e) {
        const int idx = t + e * 256;      // uint4 index in padded output row
        if (idx < 928) {
            const int wo = idx >> 4;      // pixel 0..57
            const int ch = idx & 15;      // 8-ci chunk
            uint4 pk = {0u, 0u, 0u, 0u};
            if (wo >= 1 && wo <= WW_) {
                const int wi = wo - 1;
                unsigned v[8];
                #pragma unroll
                for (int i = 0; i < 8; ++i)
                    v[i] = L[(ch * 8 + i) * LSTR + wi];
                pk.x = v[0] | (v[1] << 16);
                pk.y = v[2] | (v[3] << 16);
                pk.z = v[4] | (v[5] << 16);
                pk.w = v[6] | (v[7] << 16);
            }
            orow[idx] = pk;
        }
    }
}

// ---- main: implicit-GEMM conv, A=wb[256][1152], B=im2col rows from padded NHWC ----
__global__ __launch_bounds__(256, 4)
void conv_mfma(const unsigned short* __restrict__ wb,
               const unsigned short* __restrict__ xp,
               const float* __restrict__ bias,
               float* __restrict__ out)
{
    __shared__ __align__(16) unsigned short Asm_[BM * BK];  // 16 KB
    __shared__ __align__(16) unsigned short Bsm_[BN * BK];  // 16 KB

    const int t    = threadIdx.x;
    const int pix0 = blockIdx.x * BN;
    const int c0   = blockIdx.y * BM;

    const int slot = t & 7;
    const int r32  = t >> 3;                 // 0..31
    const int swiz = (slot ^ (r32 & 7)) * 16;

    const char* aBase = (const char*)wb + (size_t)(c0 + r32) * (KTOT * 2) + swiz;
    const char* bBase[4];
    #pragma unroll
    for (int p = 0; p < 4; ++p) {
        const int pix = pix0 + r32 + p * 32;
        const int n   = pix / PLANE;
        const int rem = pix - n * PLANE;
        const int h   = rem / WW_;
        const int w   = rem - h * WW_;
        bBase[p] = (const char*)xp + ((size_t)(n * HP + h) * HP + w) * (CIN * 2) + swiz;
    }

    const int lane = t & 63;
    const int wave = t >> 6;
    const int wm   = (wave & 1) * 64;
    const int wn   = (wave >> 1) * 64;
    const int lr   = lane & 15;
    const int quad = lane >> 4;
    const int rmod = lr & 7;

    f32x4 acc[4][4];
    #pragma unroll
    for (int i = 0; i < 4; ++i)
        #pragma unroll
        for (int j = 0; j < 4; ++j)
            acc[i][j] = (f32x4){0.f, 0.f, 0.f, 0.f};

    char* const asmb = (char*)Asm_;
    char* const bsmb = (char*)Bsm_;

    for (int tap = 0; tap < 9; ++tap) {
        const int toff = ((tap / 3) * HP + (tap % 3)) * (CIN * 2);
        for (int ci0b = 0; ci0b < 256; ci0b += 128) {
            const int abyte = tap * 256 + ci0b;
            #pragma unroll
            for (int p = 0; p < 4; ++p)
                gl_lds16(aBase + (size_t)p * 32 * (KTOT * 2) + abyte, asmb + p * 4096 + t * 16);
            #pragma unroll
            for (int p = 0; p < 4; ++p)
                gl_lds16(bBase[p] + toff + ci0b, bsmb + p * 4096 + t * 16);
            __syncthreads();

            #pragma unroll
            for (int kk = 0; kk < 2; ++kk) {
                bf16x8 af[4], bfr[4];
                #pragma unroll
                for (int i = 0; i < 4; ++i) {
                    const int r = wm + i * 16 + lr;
                    const int phys = ((kk * 4 + quad) ^ rmod) * 16;
                    af[i] = *(const bf16x8*)(asmb + r * 128 + phys);
                }
                #pragma unroll
                for (int j = 0; j < 4; ++j) {
                    const int r = wn + j * 16 + lr;
                    const int phys = ((kk * 4 + quad) ^ rmod) * 16;
                    bfr[j] = *(const bf16x8*)(bsmb + r * 128 + phys);
                }
                #pragma unroll
                for (int i = 0; i < 4; ++i)
                    #pragma unroll
                    for (int j = 0; j < 4; ++j)
                        acc[i][j] = __builtin_amdgcn_mfma_f32_16x16x32_bf16(af[i], bfr[j], acc[i][j], 0, 0, 0);
            }
            __syncthreads();
        }
    }

    // epilogue: non-temporal stores (write-once stream; keep L2 for xp)
    #pragma unroll
    for (int j = 0; j < 4; ++j) {
        const int pg    = pix0 + wn + j * 16 + lr;
        const int ni    = pg / PLANE;
        const int inner = pg - ni * PLANE;
        float* op = out + (size_t)ni * (COUT * PLANE) + inner;
        #pragma unroll
        for (int i = 0; i < 4; ++i) {
            const int crow = c0 + wm + i * 16 + quad * 4;
            #pragma unroll
            for (int r = 0; r < 4; ++r)
                __builtin_nontemporal_store(acc[i][j][r] + bias[crow + r],
                                            &op[(size_t)(crow + r) * PLANE]);
        }
    }
}

extern "C" void kernel_launch(void* const* d_in, const int* in_sizes, int n_in,
                              void* d_out, int out_size, void* d_ws, size_t ws_size,
                              hipStream_t stream) {
    const float* in   = (const float*)d_in[0];
    const float* wt   = (const float*)d_in[1];
    const float* bias = (const float*)d_in[2];
    float* out        = (float*)d_out;

    unsigned short* wb = (unsigned short*)((char*)d_ws + WB_OFF);
    unsigned short* xp = (unsigned short*)((char*)d_ws + XP_OFF);

    prep<<<NBATCH * HP + 32, 256, 0, stream>>>(in, wt, xp, wb);

    dim3 grid((NBATCH * PLANE) / BN, COUT / BM);
    conv_mfma<<<grid, 256, 0, stream>>>(wb, xp, bias, out);
}

// Round 5
// 225.698 us; speedup vs baseline: 1.1495x; 1.1495x over previous
//
#include <hip/hip_runtime.h>

#define CIN    128
#define HH     56
#define WW_    56
#define NBATCH 32
#define COUT   256
#define KTOT   1152          // 9 taps * 128 ci  (k-order: kh, kw, ci)
#define PLANE  3136          // 56*56
#define HP     58            // padded H/W
#define BM     128           // c_out tile
#define BN     128           // pixel tile
#define BK     64            // k per staging step

#define WB_OFF   0                         // bf16 weights [256][9][128] in ws
#define XP_OFF   (1u << 20)                // padded bf16 input [32][58][58][128]
#define LSTR     66                        // prep LDS stride (shorts)

typedef __attribute__((ext_vector_type(8)))  short bf16x8;
typedef __attribute__((ext_vector_type(16))) float f32x16;

__device__ __forceinline__ unsigned short f2bf(float f) {
    unsigned int u = __builtin_bit_cast(unsigned int, f);
    u += 0x7fffu + ((u >> 16) & 1u);   // RNE
    return (unsigned short)(u >> 16);
}

__device__ __forceinline__ void gl_lds16(const void* g, void* l) {
    __builtin_amdgcn_global_load_lds(
        (const __attribute__((address_space(1))) void*)g,
        (__attribute__((address_space(3))) void*)l, 16, 0, 0);
}

// ---- fused prep: blocks [0,1856) = input NCHW->padded NHWC bf16; [1856,1888) = weights ----
__global__ __launch_bounds__(256)
void prep(const float* __restrict__ in, const float* __restrict__ wt,
          unsigned short* __restrict__ xp, unsigned short* __restrict__ wb) {
    const int b = blockIdx.x;
    const int t = threadIdx.x;

    if (b >= NBATCH * HP) {               // weight conversion: 8 c_out rows per block
        const int o0 = (b - NBATCH * HP) * 8;
        for (int oo = 0; oo < 8; ++oo) {
            const float* src = wt + (size_t)(o0 + oo) * KTOT;
            unsigned short* dst = wb + (size_t)(o0 + oo) * KTOT;
            #pragma unroll
            for (int e = 0; e < 5; ++e) {
                const int idx = t + e * 256;       // = ci*9 + tap
                if (idx < KTOT) {
                    const int ci  = idx / 9;
                    const int tap = idx - ci * 9;
                    dst[tap * 128 + ci] = f2bf(src[idx]);
                }
            }
        }
        return;
    }

    const int n  = b / HP;
    const int ho = b - n * HP;
    uint4* orow = (uint4*)(xp + (((size_t)n * HP + ho) * HP) * CIN);  // 928 uint4/row

    if (ho == 0 || ho == HP - 1) {        // border rows: pure zeros
        #pragma unroll
        for (int e = 0; e < 4; ++e) {
            const int idx = t + e * 256;
            if (idx < 928) orow[idx] = (uint4){0u, 0u, 0u, 0u};
        }
        return;
    }

    __shared__ unsigned short L[CIN * LSTR];
    const int h  = ho - 1;
    const int f4 = t & 15;                // float4 slot within row (0..13 valid)
    const int cg = t >> 4;                // ci group 0..15
    if (f4 < 14) {
        const float* rowb = in + ((size_t)n * CIN) * PLANE + (size_t)h * WW_;
        #pragma unroll
        for (int g = 0; g < 8; ++g) {
            const int ci = cg + g * 16;
            const float4 v = *(const float4*)(rowb + (size_t)ci * PLANE + f4 * 4);
            unsigned lo = (unsigned)f2bf(v.x) | ((unsigned)f2bf(v.y) << 16);
            unsigned hi = (unsigned)f2bf(v.z) | ((unsigned)f2bf(v.w) << 16);
            *(unsigned*)&L[ci * LSTR + f4 * 4]     = lo;
            *(unsigned*)&L[ci * LSTR + f4 * 4 + 2] = hi;
        }
    }
    __syncthreads();

    #pragma unroll
    for (int e = 0; e < 4; ++e) {
        const int idx = t + e * 256;      // uint4 index in padded output row
        if (idx < 928) {
            const int wo = idx >> 4;      // pixel 0..57
            const int ch = idx & 15;      // 8-ci chunk
            uint4 pk = {0u, 0u, 0u, 0u};
            if (wo >= 1 && wo <= WW_) {
                const int wi = wo - 1;
                unsigned v[8];
                #pragma unroll
                for (int i = 0; i < 8; ++i)
                    v[i] = L[(ch * 8 + i) * LSTR + wi];
                pk.x = v[0] | (v[1] << 16);
                pk.y = v[2] | (v[3] << 16);
                pk.z = v[4] | (v[5] << 16);
                pk.w = v[6] | (v[7] << 16);
            }
            orow[idx] = pk;
        }
    }
}

// ---- main: implicit-GEMM conv, 32x32x16 MFMA, A=wb[256][1152], B=padded-NHWC rows ----
__global__ __launch_bounds__(256, 2)
void conv_mfma(const unsigned short* __restrict__ wb,
               const unsigned short* __restrict__ xp,
               const float* __restrict__ bias,
               float* __restrict__ out)
{
    __shared__ __align__(16) unsigned short Asm_[BM * BK];  // 16 KB, 128B rows
    __shared__ __align__(16) unsigned short Bsm_[BN * BK];  // 16 KB

    const int t    = threadIdx.x;
    const int c0   = blockIdx.x * BM;     // grid (2, 784): c-pairs adjacent -> share B in L2
    const int pix0 = blockIdx.y * BN;

    // staging: per p, rows r32+p*32; phys 16B slot = t&7, logical chunk XOR-swizzled
    const int slot = t & 7;
    const int r32  = t >> 3;
    const int swiz = (slot ^ (r32 & 7)) * 16;

    const char* aBase = (const char*)wb + (size_t)(c0 + r32) * (KTOT * 2) + swiz;
    const char* bBase[4];
    #pragma unroll
    for (int p = 0; p < 4; ++p) {
        const int pix = pix0 + r32 + p * 32;
        const int n   = pix / PLANE;
        const int rem = pix - n * PLANE;
        const int h   = rem / WW_;
        const int w   = rem - h * WW_;
        bBase[p] = (const char*)xp + ((size_t)(n * HP + h) * HP + w) * (CIN * 2) + swiz;
    }

    // compute coords (32x32 frags)
    const int lane  = t & 63;
    const int wave  = t >> 6;
    const int wm    = (wave & 1) * 64;
    const int wn    = (wave >> 1) * 64;
    const int col32 = lane & 31;
    const int khalf = lane >> 5;          // 0/1: which 8-k group

    f32x16 acc[2][2];
    #pragma unroll
    for (int i = 0; i < 2; ++i)
        #pragma unroll
        for (int j = 0; j < 2; ++j)
            #pragma unroll
            for (int r = 0; r < 16; ++r)
                acc[i][j][r] = 0.f;

    char* const asmb = (char*)Asm_;
    char* const bsmb = (char*)Bsm_;

    const int arow[2] = { wm + col32, wm + 32 + col32 };
    const int brow[2] = { wn + col32, wn + 32 + col32 };

    for (int tap = 0; tap < 9; ++tap) {
        const int toff = ((tap / 3) * HP + (tap % 3)) * (CIN * 2);
        for (int ci0b = 0; ci0b < 256; ci0b += 128) {
            const int abyte = tap * 256 + ci0b;
            #pragma unroll
            for (int p = 0; p < 4; ++p)
                gl_lds16(aBase + (size_t)p * 32 * (KTOT * 2) + abyte, asmb + p * 4096 + t * 16);
            #pragma unroll
            for (int p = 0; p < 4; ++p)
                gl_lds16(bBase[p] + toff + ci0b, bsmb + p * 4096 + t * 16);
            __syncthreads();

            #pragma unroll
            for (int s = 0; s < 4; ++s) {           // 4 k-steps of 16
                const int chunk = s * 2 + khalf;
                bf16x8 af[2], bf[2];
                #pragma unroll
                for (int i = 0; i < 2; ++i)
                    af[i] = *(const bf16x8*)(asmb + arow[i] * 128 + ((chunk ^ (arow[i] & 7)) * 16));
                #pragma unroll
                for (int j = 0; j < 2; ++j)
                    bf[j] = *(const bf16x8*)(bsmb + brow[j] * 128 + ((chunk ^ (brow[j] & 7)) * 16));
                #pragma unroll
                for (int i = 0; i < 2; ++i)
                    #pragma unroll
                    for (int j = 0; j < 2; ++j)
                        acc[i][j] = __builtin_amdgcn_mfma_f32_32x32x16_bf16(af[i], bf[j], acc[i][j], 0, 0, 0);
            }
            __syncthreads();
        }
    }

    // epilogue: D col=lane&31 (pixel), row=(reg&3)+8*(reg>>2)+4*khalf (c_out)
    float bv[2][16];
    #pragma unroll
    for (int i = 0; i < 2; ++i)
        #pragma unroll
        for (int r = 0; r < 16; ++r)
            bv[i][r] = bias[c0 + wm + i * 32 + (r & 3) + 8 * (r >> 2) + 4 * khalf];

    #pragma unroll
    for (int j = 0; j < 2; ++j) {
        const int pg    = pix0 + wn + j * 32 + col32;
        const int ni    = pg / PLANE;
        const int inner = pg - ni * PLANE;
        float* op = out + (size_t)ni * (COUT * PLANE) + inner;
        #pragma unroll
        for (int i = 0; i < 2; ++i) {
            const int cb = c0 + wm + i * 32 + 4 * khalf;
            #pragma unroll
            for (int r = 0; r < 16; ++r) {
                const int c = cb + (r & 3) + 8 * (r >> 2);
                op[(size_t)c * PLANE] = acc[i][j][r] + bv[i][r];
            }
        }
    }
}

extern "C" void kernel_launch(void* const* d_in, const int* in_sizes, int n_in,
                              void* d_out, int out_size, void* d_ws, size_t ws_size,
                              hipStream_t stream) {
    const float* in   = (const float*)d_in[0];
    const float* wt   = (const float*)d_in[1];
    const float* bias = (const float*)d_in[2];
    float* out        = (float*)d_out;

    unsigned short* wb = (unsigned short*)((char*)d_ws + WB_OFF);
    unsigned short* xp = (unsigned short*)((char*)d_ws + XP_OFF);

    prep<<<NBATCH * HP + 32, 256, 0, stream>>>(in, wt, xp, wb);

    dim3 grid(COUT / BM, (NBATCH * PLANE) / BN);
    conv_mfma<<<grid, 256, 0, stream>>>(wb, xp, bias, out);
}